// Round 2
// baseline (104.186 us; speedup 1.0000x reference)
//
#include <hip/hip_runtime.h>

// ShiftLocalAttention2d: 7x7 neighborhood attention, B=4, C=256 (8 heads x 32),
// H=W=48. fp32 in/out, fp32 accumulate. K/V staged in LDS as f16.
//
// R6: LDS-traffic cut via vertical query pairing.
//  Each lane owns TWO queries (qx, qy) and (qx, qy+1). Their 7x7 windows
//  share 6 of 8 pixel rows, so one ds_read_b128 of K (and of V) feeds both
//  score/accumulate chains: main-loop LDS traffic -43% (196 -> 112 b128 per
//  query-row-pair). Row loop = 8 rows: rr=0 serves A only, rr=7 B only,
//  rr=1..6 both — all wave-uniform branches (template<DA,DB>).
//  VALU per query unchanged (it was ~3.5us vs LDS ~8.8us).
//  Block = 16x6 queries, 3 waves (192 thr), 42KB LDS -> 3 blocks/CU, 768
//  blocks = exactly 3/CU (balanced). Summation order per query identical to
//  R5 -> bit-identical output.
// lane = part(4) x qx(16); wave = one query ROW PAIR.

#define H_IMG 48
#define W_IMG 48
#define DHEAD 32
#define NH    8
#define RAD   3
#define TW    16
#define TH    6                      // query rows per block
#define NWAVE (TH / 2)               // 3 waves, one per row pair
#define NPART 4
#define CPL   8                      // channels per lane
#define HALO_W  (TW + 2*RAD)         // 22
#define HALO_H  (TH + 2*RAD)         // 12
#define HALO_PX (HALO_W * HALO_H)    // 264
#define CSTR    40                   // shorts per pixel (80B; 16B-aligned chunks)
#define PLANE   (H_IMG * W_IMG)      // 2304
#define NTHREADS (NPART * TW * NWAVE) // 192

typedef _Float16 half_t;
typedef half_t half2_t __attribute__((ext_vector_type(2)));

// in-quad butterfly adds via DPP quad_perm (VALU pipe, not LDS)
__device__ __forceinline__ float dppadd1(float x) {   // + lane^1
  int y = __builtin_amdgcn_update_dpp(0, __float_as_int(x), 0xB1, 0xF, 0xF, true);
  return x + __int_as_float(y);
}
__device__ __forceinline__ float dppadd2(float x) {   // + lane^2
  int y = __builtin_amdgcn_update_dpp(0, __float_as_int(x), 0x4E, 0xF, 0xF, true);
  return x + __int_as_float(y);
}

// raw v_exp_f32 (2^x). Guarded: falls back to __expf(x*ln2) if builtin absent.
#if defined(__has_builtin)
#if __has_builtin(__builtin_amdgcn_exp2f)
#define EXP2F(x) __builtin_amdgcn_exp2f(x)
#endif
#endif
#ifndef EXP2F
#define EXP2F(x) __expf(0.6931471805599453f * (x))
#endif

// One halo pixel row sweep (7 rx). Reads each K/V record ONCE and feeds the
// chains of query A and/or B (compile-time selected; callers are wave-uniform).
template<bool DA, bool DB>
__device__ __forceinline__ void do_row(const unsigned short* kb,
                                       const unsigned short* vb,
                                       const half2_t* qpA, const half2_t* qpB,
                                       const float* cmf,
                                       float& denA, float* oA,
                                       float& denB, float* oB) {
#pragma unroll
  for (int rx = 0; rx < 7; ++rx) {
    union { uint4 u; half2_t h[4]; } kw, vw;
    kw.u = *(const uint4*)(kb + rx * CSTR);
    vw.u = *(const uint4*)(vb + rx * CSTR);
    if constexpr (DA) {
      float acc = __builtin_amdgcn_fdot2(qpA[0], kw.h[0], 0.0f, false);
      acc = __builtin_amdgcn_fdot2(qpA[1], kw.h[1], acc, false);
      acc = __builtin_amdgcn_fdot2(qpA[2], kw.h[2], acc, false);
      acc = __builtin_amdgcn_fdot2(qpA[3], kw.h[3], acc, false);
      acc = dppadd1(acc);
      acc = dppadd2(acc);
      const float p = EXP2F(acc) * cmf[rx];
      denA += p;
      oA[0] += p * (float)vw.h[0].x;  oA[1] += p * (float)vw.h[0].y;
      oA[2] += p * (float)vw.h[1].x;  oA[3] += p * (float)vw.h[1].y;
      oA[4] += p * (float)vw.h[2].x;  oA[5] += p * (float)vw.h[2].y;
      oA[6] += p * (float)vw.h[3].x;  oA[7] += p * (float)vw.h[3].y;
    }
    if constexpr (DB) {
      float acc = __builtin_amdgcn_fdot2(qpB[0], kw.h[0], 0.0f, false);
      acc = __builtin_amdgcn_fdot2(qpB[1], kw.h[1], acc, false);
      acc = __builtin_amdgcn_fdot2(qpB[2], kw.h[2], acc, false);
      acc = __builtin_amdgcn_fdot2(qpB[3], kw.h[3], acc, false);
      acc = dppadd1(acc);
      acc = dppadd2(acc);
      const float p = EXP2F(acc) * cmf[rx];
      denB += p;
      oB[0] += p * (float)vw.h[0].x;  oB[1] += p * (float)vw.h[0].y;
      oB[2] += p * (float)vw.h[1].x;  oB[3] += p * (float)vw.h[1].y;
      oB[4] += p * (float)vw.h[2].x;  oB[5] += p * (float)vw.h[2].y;
      oB[6] += p * (float)vw.h[3].x;  oB[7] += p * (float)vw.h[3].y;
    }
  }
}

__global__ __launch_bounds__(NTHREADS, 3)
void natten_f32_kernel(const float* __restrict__ q,
                       const float* __restrict__ k,
                       const float* __restrict__ v,
                       float* __restrict__ out) {
  __shared__ __align__(16) unsigned short kl[HALO_PX * CSTR];
  __shared__ __align__(16) unsigned short vl[HALO_PX * CSTR];

  const int part = threadIdx.x;           // 0..3  (channel quarter)
  const int qx   = threadIdx.y;           // 0..15
  const int wv   = threadIdx.z;           // 0..2  (row-pair wave)
  const int tid  = part + NPART * qx + NPART * TW * wv;
  const int x0   = blockIdx.x * TW;
  const int y0   = blockIdx.y * TH;
  const size_t cbase = (size_t)blockIdx.z * DHEAD * PLANE;

  // ---- This lane's 8 query channels for BOTH queries, pre-scaled by
  //      (1/sqrt(32))*log2(e), packed f16x2. Issued first (overlap staging).
  const int gqx = x0 + qx;
  const int gqyA = y0 + 2 * wv;
  const int gqyB = gqyA + 1;
  const float S = 0.17677669529663687f * 1.4426950408889634f;
  const size_t qoffA = cbase + (size_t)gqyA * W_IMG + gqx;
  const size_t qoffB = qoffA + W_IMG;
  half2_t qpA[4], qpB[4];
#pragma unroll
  for (int j = 0; j < 4; ++j) {
    qpA[j].x = (half_t)(q[qoffA + (size_t)(part * CPL + 2 * j) * PLANE] * S);
    qpA[j].y = (half_t)(q[qoffA + (size_t)(part * CPL + 2 * j + 1) * PLANE] * S);
    qpB[j].x = (half_t)(q[qoffB + (size_t)(part * CPL + 2 * j) * PLANE] * S);
    qpB[j].y = (half_t)(q[qoffB + (size_t)(part * CPL + 2 * j + 1) * PLANE] * S);
  }

  // ---- per-lane column mask as float {0,1}; row-invariant ----
  float cmf[7];
#pragma unroll
  for (int rx = 0; rx < 7; ++rx) {
    const int gx = gqx + rx - RAD;
    cmf[rx] = ((unsigned)gx < (unsigned)W_IMG) ? 1.0f : 0.0f;
  }

  // ---- Stage K/V halo as packed f16, one b128 (8ch) per (pixel,chunk).
  //      CLAMPED coords: OOB pixels hold valid-but-wrong data; their score
  //      is zeroed by cmf or the row skip, so never used. ----
  for (int i = tid; i < HALO_PX * 4; i += NTHREADS) {
    const int pix = i >> 2, chunk = i & 3;
    const int hy = pix / HALO_W;
    const int hx = pix - hy * HALO_W;
    int gy = y0 - RAD + hy;
    int gx = x0 - RAD + hx;
    gy = gy < 0 ? 0 : (gy > H_IMG - 1 ? H_IMG - 1 : gy);
    gx = gx < 0 ? 0 : (gx > W_IMG - 1 ? W_IMG - 1 : gx);
    const size_t g = cbase + (size_t)(chunk * CPL) * PLANE + (size_t)gy * W_IMG + gx;
    const float* kb = k + g;
    const float* vb = v + g;
    union { half2_t h2[4]; uint4 u; } kk, vv;
#pragma unroll
    for (int j = 0; j < 4; ++j) {
      half2_t a, b;
      a.x = (half_t)kb[(2 * j) * PLANE];  a.y = (half_t)kb[(2 * j + 1) * PLANE];
      b.x = (half_t)vb[(2 * j) * PLANE];  b.y = (half_t)vb[(2 * j + 1) * PLANE];
      kk.h2[j] = a;  vv.h2[j] = b;
    }
    *(uint4*)&kl[pix * CSTR + chunk * CPL] = kk.u;
    *(uint4*)&vl[pix * CSTR + chunk * CPL] = vv.u;
  }

  __syncthreads();

  float denA = 0.0f, denB = 0.0f;
  float oA[CPL], oB[CPL];
#pragma unroll
  for (int j = 0; j < CPL; ++j) { oA[j] = 0.0f; oB[j] = 0.0f; }

  // Pixel rows rr=0..7 cover the union of A's (rr=0..6) and B's (rr=1..7)
  // windows. Halo row index = 2*wv + rr (0..11). All branches wave-uniform.
  for (int rr = 0; rr < 8; ++rr) {
    const int gr = y0 + 2 * wv + rr - RAD;       // global pixel row
    if ((unsigned)gr >= (unsigned)H_IMG) continue;
    const int base = ((2 * wv + rr) * HALO_W + qx) * CSTR + part * CPL;
    const unsigned short* kb = &kl[base];
    const unsigned short* vb = &vl[base];
    if (rr == 0)
      do_row<true, false>(kb, vb, qpA, qpB, cmf, denA, oA, denB, oB);
    else if (rr == 7)
      do_row<false, true>(kb, vb, qpA, qpB, cmf, denA, oA, denB, oB);
    else
      do_row<true, true>(kb, vb, qpA, qpB, cmf, denA, oA, denB, oB);
  }

  const float rdenA = 1.0f / denA;         // den >= exp(center score) > 0
  const float rdenB = 1.0f / denB;
#pragma unroll
  for (int j = 0; j < CPL; ++j) {
    out[qoffA + (size_t)(part * CPL + j) * PLANE] = oA[j] * rdenA;
    out[qoffB + (size_t)(part * CPL + j) * PLANE] = oB[j] * rdenB;
  }
}

extern "C" void kernel_launch(void* const* d_in, const int* in_sizes, int n_in,
                              void* d_out, int out_size, void* d_ws, size_t ws_size,
                              hipStream_t stream) {
  const float* q = (const float*)d_in[0];
  const float* k = (const float*)d_in[1];
  const float* v = (const float*)d_in[2];
  float* out = (float*)d_out;

  dim3 grid(W_IMG / TW, H_IMG / TH, 4 * NH);   // (3, 8, 32) = 768 blocks
  dim3 block(NPART, TW, NWAVE);                 // 192 threads = 3 waves
  hipLaunchKernelGGL(natten_f32_kernel, grid, block, 0, stream, q, k, v, out);
}

// Round 5
// 96.493 us; speedup vs baseline: 1.0797x; 1.0797x over previous
//
#include <hip/hip_runtime.h>

// ShiftLocalAttention2d: 7x7 neighborhood attention, B=4, C=256 (8 heads x 32),
// H=W=48. fp32 in/out, f16 MFMA compute, f32 accumulate.
//
// R7c: MFMA rewrite, mask fix. R7b scored every query against all 22 keys of
// the halo row but only masked "key in halo / in image" — missing the
// per-query 7-wide window. Fixed: cm[t][r] also requires krel - c in [0,6]
// (krel = t*16 + 4p + r is this lane's key slot, c its query column).
//  QK^T swapped: S^T[key][q] = mfma_16x16x32_f16(A=K[16key x 32ch] from kl,
//    B=Q^T[32ch x 16q] in regs). 2 tiles cover the 22-key row span.
//  C-layout (m89): col=lane&15=q, row=4*(lane>>4)+reg=key.
//  Softmax: plain exp2 (Q pre-scaled by rsqrt(32)*log2e), no max pass; mask
//    folded as {0,1} float multiply; den: per-lane partial + 2 shuffles.
//  P^T repack: cvt_pkrtz f32->f16, ds_write into per-wave [q][kslot] buffer,
//    ds_read_b128 back as PV B-frag. Same-wave DS ordering => no barrier.
//  PV: out^T[ch][q] += mfma(A=V^T[16ch x 32kslot] from vlT, B=P^T).
//  A/B both packed with the same ascending logical-k order => HW internal
//  k-permutation cancels; only the HW-verified C/D layout is assumed.
//  All LDS overreach (kl pad pixels, vlT channel pad) zeroed; out-of-window
//  kslots (incl. vlT p=3 row-overlap reads) are finite * 0.0.
// LDS 48.5 KB -> 3 blocks/CU -> 18 waves/CU.

#define H_IMG 48
#define W_IMG 48
#define DHEAD 32
#define NH    8
#define RAD   3
#define TW    16
#define TH    6
#define NWAVES TH                     // one wave per query row
#define NTHREADS (64 * NWAVES)        // 384
#define HALO_W  (TW + 2*RAD)          // 22
#define HALO_H  (TH + 2*RAD)          // 12
#define HALO_PX (HALO_W * HALO_H)     // 264
#define KL_PX   (HALO_PX + 10)        // tile1 overreach: hrow=11 reads px<=273
#define KSTR    40                    // shorts per pixel in kl (80 B, 16B chunks)
#define VROW    24                    // key slots per halo row in vlT
#define VSTR    (HALO_H * VROW + 8)   // 296 shorts per channel (592 B, 16B-mult)
#define PSTR    40                    // shorts per q-row in ps (80 B)
#define PLANE   (H_IMG * W_IMG)       // 2304

typedef _Float16 half_t;
typedef half_t half8_t __attribute__((ext_vector_type(8)));
typedef __fp16 fp16x2_t __attribute__((ext_vector_type(2)));  // cvt_pkrtz type
typedef float  f32x4  __attribute__((ext_vector_type(4)));

// raw v_exp_f32 (2^x). Guarded: falls back to __expf(x*ln2) if builtin absent.
#if defined(__has_builtin)
#if __has_builtin(__builtin_amdgcn_exp2f)
#define EXP2F(x) __builtin_amdgcn_exp2f(x)
#endif
#endif
#ifndef EXP2F
#define EXP2F(x) __expf(0.6931471805599453f * (x))
#endif

__global__ __launch_bounds__(NTHREADS, 3)
void natten_f32_kernel(const float* __restrict__ q,
                       const float* __restrict__ k,
                       const float* __restrict__ v,
                       float* __restrict__ out) {
  // K: per-pixel packed [px][32ch f16 + pad]  (A-frag for QK^T)
  __shared__ __align__(16) unsigned short kl[KL_PX * KSTR];        // 21.9 KB
  // V^T: [32ch][12 rows][24 slots] + 8 pad shorts/ch  (A-frag for PV)
  __shared__ __align__(16) unsigned short vlT[DHEAD * VSTR];       // 18.9 KB
  // P^T repack: per wave [16 q][40 shorts]  (B-frag for PV)
  __shared__ __align__(16) unsigned short ps[NWAVES * 16 * PSTR];  //  7.7 KB

  const int lane = threadIdx.x;        // 0..63
  const int wv   = threadIdx.y;        // 0..5  (query row within tile)
  const int tid  = lane + 64 * wv;
  const int c    = lane & 15;          // q column / D col
  const int p    = lane >> 4;          // k-slot group / D row group
  const int x0   = blockIdx.x * TW;
  const int y0   = blockIdx.y * TH;
  const size_t cbase = (size_t)blockIdx.z * DHEAD * PLANE;

  const int gqx = x0 + c;
  const int gqy = y0 + wv;

  // ---- Q B-frag: lane holds Q[q=c][ch = 8p..8p+7], pre-scaled ----
  const float S = 0.17677669529663687f * 1.4426950408889634f; // rsqrt(32)*log2e
  const size_t qoff = cbase + (size_t)gqy * W_IMG + gqx;
  half8_t qf;
#pragma unroll
  for (int j = 0; j < 8; ++j)
    qf[j] = (half_t)(q[qoff + (size_t)(p * 8 + j) * PLANE] * S);

  // ---- mask per (tile, reg): key slot krel = t*16 + 4p + r is valid for
  //      query c iff krel-c in [0,6] (7-wide window) and its gx is in-image.
  float cm[2][4];
#pragma unroll
  for (int t = 0; t < 2; ++t)
#pragma unroll
    for (int r = 0; r < 4; ++r) {
      const int krel = t * 16 + 4 * p + r;
      const int gx = x0 + krel - RAD;
      cm[t][r] = ((unsigned)(krel - c) <= 6u &&
                  (unsigned)gx < (unsigned)W_IMG) ? 1.0f : 0.0f;
    }

  // ---- stage K: packed f16 per pixel (clamped coords; OOB masked later) ----
  for (int i = tid; i < HALO_PX * 4; i += NTHREADS) {
    const int pix = i >> 2, chunk = i & 3;
    const int hy = pix / HALO_W;
    const int hx = pix - hy * HALO_W;
    int gy = y0 - RAD + hy;
    int gx = x0 - RAD + hx;
    gy = gy < 0 ? 0 : (gy > H_IMG - 1 ? H_IMG - 1 : gy);
    gx = gx < 0 ? 0 : (gx > W_IMG - 1 ? W_IMG - 1 : gx);
    const float* kb = k + cbase + (size_t)(chunk * 8) * PLANE + (size_t)gy * W_IMG + gx;
    union { half_t h[8]; uint4 u; } kk;
#pragma unroll
    for (int j = 0; j < 8; ++j) kk.h[j] = (half_t)kb[(size_t)j * PLANE];
    *(uint4*)&kl[pix * KSTR + chunk * 8] = kk.u;
  }
  // zero kl pad pixels (read by tile1 at hrow=11; must be finite)
  if (tid < (KL_PX - HALO_PX) * (KSTR / 8)) {            // 10 px * 5 uint4
    const uint4 z = make_uint4(0, 0, 0, 0);
    *(uint4*)&kl[HALO_PX * KSTR + tid * 8] = z;
  }

  // ---- stage V^T: [ch][row][slot], one b128 (8 slots) per iteration ----
  for (int i = tid; i < DHEAD * HALO_H * 3; i += NTHREADS) {   // 1152
    const int ch = i / (HALO_H * 3);
    const int rem = i - ch * (HALO_H * 3);
    const int row = rem / 3, oct = rem - row * 3;
    int gy = y0 - RAD + row;
    gy = gy < 0 ? 0 : (gy > H_IMG - 1 ? H_IMG - 1 : gy);
    const float* vb = v + cbase + (size_t)ch * PLANE + (size_t)gy * W_IMG;
    union { half_t h[8]; uint4 u; } vv;
#pragma unroll
    for (int j = 0; j < 8; ++j) {
      int s = oct * 8 + j;                 // slot 0..23; 22,23 are dup/masked
      int hx = s > 21 ? 21 : s;
      int gx = x0 - RAD + hx;
      gx = gx < 0 ? 0 : (gx > W_IMG - 1 ? W_IMG - 1 : gx);
      vv.h[j] = (half_t)vb[gx];
    }
    *(uint4*)&vlT[ch * VSTR + row * VROW + oct * 8] = vv.u;
  }
  // zero vlT per-channel pad (overread by p=3 frag at row 11)
  if (tid < DHEAD) {
    const uint4 z = make_uint4(0, 0, 0, 0);
    *(uint4*)&vlT[tid * VSTR + HALO_H * VROW] = z;
  }

  __syncthreads();

  f32x4 oa0 = {0.f, 0.f, 0.f, 0.f};
  f32x4 oa1 = {0.f, 0.f, 0.f, 0.f};
  const f32x4 z4 = {0.f, 0.f, 0.f, 0.f};
  float den = 0.0f;

  unsigned short* psq = &ps[(wv * 16 + c) * PSTR];   // this lane's q-row

  for (int ry = 0; ry < 7; ++ry) {
    const int gy = gqy + ry - RAD;
    if ((unsigned)gy >= (unsigned)H_IMG) continue;   // uniform per wave
    const int hrow = wv + ry;                        // 0..11

    // K A-frags: tile0 keys hx 0..15, tile1 keys hx 16..31 (tail masked)
    union { uint4 u; half8_t h; } ka0, ka1, va0, va1, pb;
    ka0.u = *(const uint4*)&kl[(hrow * HALO_W + c) * KSTR + p * 8];
    ka1.u = *(const uint4*)&kl[(hrow * HALO_W + 16 + c) * KSTR + p * 8];
    // V^T A-frags: ch=c and ch=16+c, kslots 8p..8p+7 of this halo row
    va0.u = *(const uint4*)&vlT[c * VSTR + hrow * VROW + p * 8];
    va1.u = *(const uint4*)&vlT[(16 + c) * VSTR + hrow * VROW + p * 8];

    // S^T = K . Q^T   (col = q, row = key)
    f32x4 s0 = __builtin_amdgcn_mfma_f32_16x16x32_f16(ka0.h, qf, z4, 0, 0, 0);
    f32x4 s1 = __builtin_amdgcn_mfma_f32_16x16x32_f16(ka1.h, qf, z4, 0, 0, 0);

    // p = exp2(s) * mask; accumulate den; pack to f16 pairs
    float pe0[4], pe1[4];
#pragma unroll
    for (int r = 0; r < 4; ++r) {
      pe0[r] = EXP2F(s0[r]) * cm[0][r];
      pe1[r] = EXP2F(s1[r]) * cm[1][r];
      den += pe0[r] + pe1[r];
    }
    union { fp16x2_t h[2]; uint2 u; } w0, w1;
    w0.h[0] = __builtin_amdgcn_cvt_pkrtz(pe0[0], pe0[1]);
    w0.h[1] = __builtin_amdgcn_cvt_pkrtz(pe0[2], pe0[3]);
    w1.h[0] = __builtin_amdgcn_cvt_pkrtz(pe1[0], pe1[1]);
    w1.h[1] = __builtin_amdgcn_cvt_pkrtz(pe1[2], pe1[3]);
    // P^T[kslot][q]: lane's 4 keys of tile t live at bytes t*32 + p*8 (+h*4)
    *(uint2*)((char*)psq + p * 8)      = w0.u;
    *(uint2*)((char*)psq + 32 + p * 8) = w1.u;

    // B-frag: kslots 8p..8p+7 of this q-row (same-wave DS => ordered)
    pb.u = *(const uint4*)((const char*)psq + p * 16);

    // out^T += V^T . P^T
    oa0 = __builtin_amdgcn_mfma_f32_16x16x32_f16(va0.h, pb.h, oa0, 0, 0, 0);
    oa1 = __builtin_amdgcn_mfma_f32_16x16x32_f16(va1.h, pb.h, oa1, 0, 0, 0);
  }

  // den: lane holds partial over its 8 (tile,reg) keys; sum the 4 p-groups
  den += __shfl_xor(den, 16);
  den += __shfl_xor(den, 32);
  const float rden = 1.0f / den;       // den >= exp(center score) > 0

  // D layout: col=c=q, row=4p+r = ch (tile0: ch 0..15, tile1: ch 16..31)
  const size_t obase = cbase + (size_t)gqy * W_IMG + x0 + c;
#pragma unroll
  for (int r = 0; r < 4; ++r) {
    out[obase + (size_t)(4 * p + r) * PLANE]      = oa0[r] * rden;
    out[obase + (size_t)(16 + 4 * p + r) * PLANE] = oa1[r] * rden;
  }
}

extern "C" void kernel_launch(void* const* d_in, const int* in_sizes, int n_in,
                              void* d_out, int out_size, void* d_ws, size_t ws_size,
                              hipStream_t stream) {
  const float* q = (const float*)d_in[0];
  const float* k = (const float*)d_in[1];
  const float* v = (const float*)d_in[2];
  float* out = (float*)d_out;

  dim3 grid(W_IMG / TW, H_IMG / TH, 4 * NH);   // (3, 8, 32) = 768 blocks
  dim3 block(64, NWAVES, 1);                    // 384 threads = 6 waves
  hipLaunchKernelGGL(natten_f32_kernel, grid, block, 0, stream, q, k, v, out);
}

// Round 6
// 94.779 us; speedup vs baseline: 1.0992x; 1.0181x over previous
//
#include <hip/hip_runtime.h>

// ShiftLocalAttention2d: 7x7 neighborhood attention, B=4, C=256 (8 heads x 32),
// H=W=48. fp32 in/out, f16 MFMA compute, f32 accumulate.
//
// R8: kill the P->LDS round-trip; branch-free unrolled main loop.
//  - PV uses mfma_f32_16x16x16f16 pairs: B-frag lane (c,p) holds k=4p..4p+3,
//    which is exactly the 4 P values this lane computed from QK^T's C-rows
//    (row=4p+r). cvt_pkrtz pairs feed the MFMA directly from registers ->
//    no ps buffer, no ds_write/ds_read RAW chain per iteration.
//  - V^T A-frags: 4x ds_read_b64 (kslots 4p..4p+3 and 16+4p..+3, ch=c and
//    16+c). Overreads (kslots>21, hrow=11 tail) land in masked/zeroed slots.
//  - Row validity folded into the QK MFMA C operand as a -16384 bias
//    (exp2 underflows to exact 0) -> no uniform continue; 7-iter loop fully
//    unrolled, compiler can pipeline LDS reads/MFMA/VALU across iterations.
//  - ps removed: LDS 40.9 KB; launch_bounds(384,5) caps VGPR at 102 so
//    >=3 blocks/CU (4 if allocator lands <=85).
//  QK^T unchanged from R7c: S^T[key][q] = mfma_16x16x32_f16(A=K from kl,
//    B=Q^T in regs); mask krel-c in [0,6] && gx in-image as {0,1} float.
// lane = (c = q column, p = key/ch quad); wave = one query row; 16x6 tile.

#define H_IMG 48
#define W_IMG 48
#define DHEAD 32
#define NH    8
#define RAD   3
#define TW    16
#define TH    6
#define NWAVES TH                     // one wave per query row
#define NTHREADS (64 * NWAVES)        // 384
#define HALO_W  (TW + 2*RAD)          // 22
#define HALO_H  (TH + 2*RAD)          // 12
#define HALO_PX (HALO_W * HALO_H)     // 264
#define KL_PX   (HALO_PX + 10)        // tile1 overreach: hrow=11 reads px<=273
#define KSTR    40                    // shorts per pixel in kl (80 B, 16B chunks)
#define VROW    24                    // key slots per halo row in vlT
#define VSTR    (HALO_H * VROW + 8)   // 296 shorts per channel (592 B)
#define PLANE   (H_IMG * W_IMG)       // 2304

typedef _Float16 half_t;
typedef half_t half4_t __attribute__((ext_vector_type(4)));
typedef half_t half8_t __attribute__((ext_vector_type(8)));
typedef __fp16 fp16x2_t __attribute__((ext_vector_type(2)));  // cvt_pkrtz type
typedef float  f32x4  __attribute__((ext_vector_type(4)));

// raw v_exp_f32 (2^x). Guarded: falls back to __expf(x*ln2) if builtin absent.
#if defined(__has_builtin)
#if __has_builtin(__builtin_amdgcn_exp2f)
#define EXP2F(x) __builtin_amdgcn_exp2f(x)
#endif
#endif
#ifndef EXP2F
#define EXP2F(x) __expf(0.6931471805599453f * (x))
#endif

__global__ __launch_bounds__(NTHREADS, 5)
void natten_f32_kernel(const float* __restrict__ q,
                       const float* __restrict__ k,
                       const float* __restrict__ v,
                       float* __restrict__ out) {
  // K: per-pixel packed [px][32ch f16 + pad]  (A-frag for QK^T)
  __shared__ __align__(16) unsigned short kl[KL_PX * KSTR];        // 21.9 KB
  // V^T: [32ch][12 rows][24 slots] + 8 pad shorts/ch  (A-frag for PV)
  __shared__ __align__(16) unsigned short vlT[DHEAD * VSTR];       // 18.9 KB

  const int lane = threadIdx.x;        // 0..63
  const int wv   = threadIdx.y;        // 0..5  (query row within tile)
  const int tid  = lane + 64 * wv;
  const int c    = lane & 15;          // q column / D col
  const int p    = lane >> 4;          // key/ch quad (k-block index)
  const int x0   = blockIdx.x * TW;
  const int y0   = blockIdx.y * TH;
  const size_t cbase = (size_t)blockIdx.z * DHEAD * PLANE;

  const int gqx = x0 + c;
  const int gqy = y0 + wv;

  // ---- Q B-frag: lane holds Q[q=c][ch = 8p..8p+7], pre-scaled ----
  const float S = 0.17677669529663687f * 1.4426950408889634f; // rsqrt(32)*log2e
  const size_t qoff = cbase + (size_t)gqy * W_IMG + gqx;
  half8_t qf;
#pragma unroll
  for (int j = 0; j < 8; ++j)
    qf[j] = (half_t)(q[qoff + (size_t)(p * 8 + j) * PLANE] * S);

  // ---- mask per (tile, reg): key slot krel = t*16 + 4p + r is valid for
  //      query c iff krel-c in [0,6] (7-wide window) and its gx is in-image.
  float cm[2][4];
#pragma unroll
  for (int t = 0; t < 2; ++t)
#pragma unroll
    for (int r = 0; r < 4; ++r) {
      const int krel = t * 16 + 4 * p + r;
      const int gx = x0 + krel - RAD;
      cm[t][r] = ((unsigned)(krel - c) <= 6u &&
                  (unsigned)gx < (unsigned)W_IMG) ? 1.0f : 0.0f;
    }

  // ---- stage K: packed f16 per pixel (clamped coords; OOB masked later) ----
  for (int i = tid; i < HALO_PX * 4; i += NTHREADS) {
    const int pix = i >> 2, chunk = i & 3;
    const int hy = pix / HALO_W;
    const int hx = pix - hy * HALO_W;
    int gy = y0 - RAD + hy;
    int gx = x0 - RAD + hx;
    gy = gy < 0 ? 0 : (gy > H_IMG - 1 ? H_IMG - 1 : gy);
    gx = gx < 0 ? 0 : (gx > W_IMG - 1 ? W_IMG - 1 : gx);
    const float* kb = k + cbase + (size_t)(chunk * 8) * PLANE + (size_t)gy * W_IMG + gx;
    union { half_t h[8]; uint4 u; } kk;
#pragma unroll
    for (int j = 0; j < 8; ++j) kk.h[j] = (half_t)kb[(size_t)j * PLANE];
    *(uint4*)&kl[pix * KSTR + chunk * 8] = kk.u;
  }
  // zero kl pad pixels (read by tile1 at hrow=11; must be finite)
  if (tid < (KL_PX - HALO_PX) * (KSTR / 8)) {            // 10 px * 5 uint4
    const uint4 z = make_uint4(0, 0, 0, 0);
    *(uint4*)&kl[HALO_PX * KSTR + tid * 8] = z;
  }

  // ---- stage V^T: [ch][row][slot], one b128 (8 slots) per iteration ----
  for (int i = tid; i < DHEAD * HALO_H * 3; i += NTHREADS) {   // 1152
    const int ch = i / (HALO_H * 3);
    const int rem = i - ch * (HALO_H * 3);
    const int row = rem / 3, oct = rem - row * 3;
    int gy = y0 - RAD + row;
    gy = gy < 0 ? 0 : (gy > H_IMG - 1 ? H_IMG - 1 : gy);
    const float* vb = v + cbase + (size_t)ch * PLANE + (size_t)gy * W_IMG;
    union { half_t h[8]; uint4 u; } vv;
#pragma unroll
    for (int j = 0; j < 8; ++j) {
      int s = oct * 8 + j;                 // slot 0..23; 22,23 are dup/masked
      int hx = s > 21 ? 21 : s;
      int gx = x0 - RAD + hx;
      gx = gx < 0 ? 0 : (gx > W_IMG - 1 ? W_IMG - 1 : gx);
      vv.h[j] = (half_t)vb[gx];
    }
    *(uint4*)&vlT[ch * VSTR + row * VROW + oct * 8] = vv.u;
  }
  // zero vlT per-channel pad (overread by p>=2 tile1 frags at row 11)
  if (tid < DHEAD) {
    const uint4 z = make_uint4(0, 0, 0, 0);
    *(uint4*)&vlT[tid * VSTR + HALO_H * VROW] = z;
  }

  __syncthreads();

  f32x4 oa0 = {0.f, 0.f, 0.f, 0.f};
  f32x4 oa1 = {0.f, 0.f, 0.f, 0.f};
  float den = 0.0f;

  // per-lane LDS bases (byte math folded by compiler into ds offsets)
  const unsigned short* klrow  = &kl[c * KSTR + p * 8];
  const unsigned short* klrow1 = &kl[(16 + c) * KSTR + p * 8];
  const unsigned short* v0row  = &vlT[c * VSTR + 4 * p];
  const unsigned short* v1row  = &vlT[(16 + c) * VSTR + 4 * p];

#pragma unroll
  for (int ry = 0; ry < 7; ++ry) {
    const int hrow = wv + ry;                        // 0..11
    // row-validity folded into QK C operand: invalid -> -16384 bias,
    // exp2(-16384 + s) == 0 exactly (|s| << 150).
    const int gy = gqy + ry - RAD;
    const float bias = ((unsigned)gy < (unsigned)H_IMG) ? 0.0f : -16384.0f;
    const f32x4 ci = {bias, bias, bias, bias};

    // K A-frags: tile0 keys hx 0..15, tile1 keys hx 16..31 (tail masked)
    union { uint4 u; half8_t h; } ka0, ka1;
    ka0.u = *(const uint4*)(klrow  + hrow * (HALO_W * KSTR));
    ka1.u = *(const uint4*)(klrow1 + hrow * (HALO_W * KSTR));

    // V^T A-frags: 4 f16 each — (ch=c / 16+c) x (kslots 4p.. / 16+4p..)
    union { uint2 u; half4_t h; } va00, va01, va10, va11;
    va00.u = *(const uint2*)(v0row + hrow * VROW);
    va01.u = *(const uint2*)(v0row + hrow * VROW + 16);
    va10.u = *(const uint2*)(v1row + hrow * VROW);
    va11.u = *(const uint2*)(v1row + hrow * VROW + 16);

    // S^T = K . Q^T + bias   (col = q, row = key)
    f32x4 s0 = __builtin_amdgcn_mfma_f32_16x16x32_f16(ka0.h, qf, ci, 0, 0, 0);
    f32x4 s1 = __builtin_amdgcn_mfma_f32_16x16x32_f16(ka1.h, qf, ci, 0, 0, 0);

    // p = exp2(s) * mask; accumulate den; pack to f16 pairs (B-frags)
    float pe0[4], pe1[4];
#pragma unroll
    for (int r = 0; r < 4; ++r) {
      pe0[r] = EXP2F(s0[r]) * cm[0][r];
      pe1[r] = EXP2F(s1[r]) * cm[1][r];
      den += pe0[r] + pe1[r];
    }
    union { fp16x2_t h2[2]; half4_t h4; } w0, w1;
    w0.h2[0] = __builtin_amdgcn_cvt_pkrtz(pe0[0], pe0[1]);
    w0.h2[1] = __builtin_amdgcn_cvt_pkrtz(pe0[2], pe0[3]);
    w1.h2[0] = __builtin_amdgcn_cvt_pkrtz(pe1[0], pe1[1]);
    w1.h2[1] = __builtin_amdgcn_cvt_pkrtz(pe1[2], pe1[3]);

    // out^T += V^T . P^T ; lane (c,p) feeds its OWN P values as B-frag
    // (16x16x16 B layout: k = 4*(l>>4)+e = krel 4p+e, t*16 offset per tile)
    oa0 = __builtin_amdgcn_mfma_f32_16x16x16f16(va00.h, w0.h4, oa0, 0, 0, 0);
    oa0 = __builtin_amdgcn_mfma_f32_16x16x16f16(va01.h, w1.h4, oa0, 0, 0, 0);
    oa1 = __builtin_amdgcn_mfma_f32_16x16x16f16(va10.h, w0.h4, oa1, 0, 0, 0);
    oa1 = __builtin_amdgcn_mfma_f32_16x16x16f16(va11.h, w1.h4, oa1, 0, 0, 0);
  }

  // den: lane holds partial over its 8 (tile,reg) keys; sum the 4 p-groups
  den += __shfl_xor(den, 16);
  den += __shfl_xor(den, 32);
  const float rden = 1.0f / den;       // den >= exp(center score) > 0

  // D layout: col=c=q, row=4p+r = ch (oa0: ch 0..15, oa1: ch 16..31)
  const size_t obase = cbase + (size_t)gqy * W_IMG + x0 + c;
#pragma unroll
  for (int r = 0; r < 4; ++r) {
    out[obase + (size_t)(4 * p + r) * PLANE]      = oa0[r] * rden;
    out[obase + (size_t)(16 + 4 * p + r) * PLANE] = oa1[r] * rden;
  }
}

extern "C" void kernel_launch(void* const* d_in, const int* in_sizes, int n_in,
                              void* d_out, int out_size, void* d_ws, size_t ws_size,
                              hipStream_t stream) {
  const float* q = (const float*)d_in[0];
  const float* k = (const float*)d_in[1];
  const float* v = (const float*)d_in[2];
  float* out = (float*)d_out;

  dim3 grid(W_IMG / TW, H_IMG / TH, 4 * NH);   // (3, 8, 32) = 768 blocks
  dim3 block(64, NWAVES, 1);                    // 384 threads = 6 waves
  hipLaunchKernelGGL(natten_f32_kernel, grid, block, 0, stream, q, k, v, out);
}

// Round 7
// 93.989 us; speedup vs baseline: 1.1085x; 1.0084x over previous
//
#include <hip/hip_runtime.h>

// ShiftLocalAttention2d: 7x7 neighborhood attention, B=4, C=256 (8 heads x 32),
// H=W=48. fp32 in/out, f16 MFMA compute, f32 accumulate.
//
// R9: T14 async-stage split (issue-early / write-late), only change vs R8:
//  V (and Q) global loads issue FIRST, converted to packed f16 in 12 regs;
//  K staging runs next (its work hides V's HBM latency); V's 3 ds_write_b128
//  land just before the single barrier. Main loop byte-identical to R8.
//  R8 recap:
//  - QK^T swapped: S^T[key][q] = mfma_16x16x32_f16(A=K from kl, B=Q^T regs),
//    2 tiles; mask (krel-c in [0,6] && gx in-image) as {0,1} float mul.
//  - Row validity folded into QK C operand (-16384 bias -> exp2 == 0).
//  - PV via mfma_16x16x16f16 pairs: lane (c,p) feeds its OWN P quad (C-rows
//    4p+r of QK^T) straight from cvt_pkrtz regs as the B-frag; V^T A-frags
//    are 4x ds_read_b64 from vlT. No P LDS round-trip.
//  - All LDS overreach (kl pad px, vlT ch pad) zeroed; out-of-window kslots
//    are finite * 0.0.
// lane = (c = q column, p = key/ch quad); wave = one query row; 16x6 tile.
// LDS 40.9 KB -> 3 blocks/CU (18 waves/CU); launch_bounds(384,5) caps VGPR 102.

#define H_IMG 48
#define W_IMG 48
#define DHEAD 32
#define NH    8
#define RAD   3
#define TW    16
#define TH    6
#define NWAVES TH                     // one wave per query row
#define NTHREADS (64 * NWAVES)        // 384
#define HALO_W  (TW + 2*RAD)          // 22
#define HALO_H  (TH + 2*RAD)          // 12
#define HALO_PX (HALO_W * HALO_H)     // 264
#define KL_PX   (HALO_PX + 10)        // tile1 overreach: hrow=11 reads px<=273
#define KSTR    40                    // shorts per pixel in kl (80 B, 16B chunks)
#define VROW    24                    // key slots per halo row in vlT
#define VSTR    (HALO_H * VROW + 8)   // 296 shorts per channel (592 B)
#define PLANE   (H_IMG * W_IMG)       // 2304
#define VITEMS  3                     // DHEAD*HALO_H*3 / NTHREADS = 1152/384

typedef _Float16 half_t;
typedef half_t half4_t __attribute__((ext_vector_type(4)));
typedef half_t half8_t __attribute__((ext_vector_type(8)));
typedef __fp16 fp16x2_t __attribute__((ext_vector_type(2)));  // cvt_pkrtz type
typedef float  f32x4  __attribute__((ext_vector_type(4)));

// raw v_exp_f32 (2^x). Guarded: falls back to __expf(x*ln2) if builtin absent.
#if defined(__has_builtin)
#if __has_builtin(__builtin_amdgcn_exp2f)
#define EXP2F(x) __builtin_amdgcn_exp2f(x)
#endif
#endif
#ifndef EXP2F
#define EXP2F(x) __expf(0.6931471805599453f * (x))
#endif

__global__ __launch_bounds__(NTHREADS, 5)
void natten_f32_kernel(const float* __restrict__ q,
                       const float* __restrict__ k,
                       const float* __restrict__ v,
                       float* __restrict__ out) {
  // K: per-pixel packed [px][32ch f16 + pad]  (A-frag for QK^T)
  __shared__ __align__(16) unsigned short kl[KL_PX * KSTR];        // 21.9 KB
  // V^T: [32ch][12 rows][24 slots] + 8 pad shorts/ch  (A-frag for PV)
  __shared__ __align__(16) unsigned short vlT[DHEAD * VSTR];       // 18.9 KB

  const int lane = threadIdx.x;        // 0..63
  const int wv   = threadIdx.y;        // 0..5  (query row within tile)
  const int tid  = lane + 64 * wv;
  const int c    = lane & 15;          // q column / D col
  const int p    = lane >> 4;          // key/ch quad (k-block index)
  const int x0   = blockIdx.x * TW;
  const int y0   = blockIdx.y * TH;
  const size_t cbase = (size_t)blockIdx.z * DHEAD * PLANE;

  const int gqx = x0 + c;
  const int gqy = y0 + wv;

  // ==== ISSUE-EARLY phase: Q and V global loads first ====

  // ---- Q B-frag: lane holds Q[q=c][ch = 8p..8p+7], pre-scaled ----
  const float S = 0.17677669529663687f * 1.4426950408889634f; // rsqrt(32)*log2e
  const size_t qoff = cbase + (size_t)gqy * W_IMG + gqx;
  half8_t qf;
#pragma unroll
  for (int j = 0; j < 8; ++j)
    qf[j] = (half_t)(q[qoff + (size_t)(p * 8 + j) * PLANE] * S);

  // ---- V loads -> packed f16 regs (VITEMS x 8 ch); ds_write deferred ----
  union { half_t h[8]; uint4 u; } vstage[VITEMS];
#pragma unroll
  for (int it = 0; it < VITEMS; ++it) {
    const int i = tid + NTHREADS * it;             // 0..1151
    const int ch = i / (HALO_H * 3);
    const int rem = i - ch * (HALO_H * 3);
    const int row = rem / 3, oct = rem - row * 3;
    int gy = y0 - RAD + row;
    gy = gy < 0 ? 0 : (gy > H_IMG - 1 ? H_IMG - 1 : gy);
    const float* vb = v + cbase + (size_t)ch * PLANE + (size_t)gy * W_IMG;
#pragma unroll
    for (int j = 0; j < 8; ++j) {
      int s = oct * 8 + j;               // slot 0..23; 22,23 are dup/masked
      int hx = s > 21 ? 21 : s;
      int gx = x0 - RAD + hx;
      gx = gx < 0 ? 0 : (gx > W_IMG - 1 ? W_IMG - 1 : gx);
      vstage[it].h[j] = (half_t)vb[gx];
    }
  }

  // ---- mask per (tile, reg): key slot krel = t*16 + 4p + r is valid for
  //      query c iff krel-c in [0,6] (7-wide window) and its gx is in-image.
  float cm[2][4];
#pragma unroll
  for (int t = 0; t < 2; ++t)
#pragma unroll
    for (int r = 0; r < 4; ++r) {
      const int krel = t * 16 + 4 * p + r;
      const int gx = x0 + krel - RAD;
      cm[t][r] = ((unsigned)(krel - c) <= 6u &&
                  (unsigned)gx < (unsigned)W_IMG) ? 1.0f : 0.0f;
    }

  // ==== K staging (hides V/Q latency) ====
  for (int i = tid; i < HALO_PX * 4; i += NTHREADS) {
    const int pix = i >> 2, chunk = i & 3;
    const int hy = pix / HALO_W;
    const int hx = pix - hy * HALO_W;
    int gy = y0 - RAD + hy;
    int gx = x0 - RAD + hx;
    gy = gy < 0 ? 0 : (gy > H_IMG - 1 ? H_IMG - 1 : gy);
    gx = gx < 0 ? 0 : (gx > W_IMG - 1 ? W_IMG - 1 : gx);
    const float* kb = k + cbase + (size_t)(chunk * 8) * PLANE + (size_t)gy * W_IMG + gx;
    union { half_t h[8]; uint4 u; } kk;
#pragma unroll
    for (int j = 0; j < 8; ++j) kk.h[j] = (half_t)kb[(size_t)j * PLANE];
    *(uint4*)&kl[pix * KSTR + chunk * 8] = kk.u;
  }
  // zero kl pad pixels (read by tile1 at hrow=11; must be finite)
  if (tid < (KL_PX - HALO_PX) * (KSTR / 8)) {            // 10 px * 5 uint4
    const uint4 z = make_uint4(0, 0, 0, 0);
    *(uint4*)&kl[HALO_PX * KSTR + tid * 8] = z;
  }

  // ==== WRITE-LATE phase: V regs -> vlT ====
#pragma unroll
  for (int it = 0; it < VITEMS; ++it) {
    const int i = tid + NTHREADS * it;
    const int ch = i / (HALO_H * 3);
    const int rem = i - ch * (HALO_H * 3);
    const int row = rem / 3, oct = rem - row * 3;
    *(uint4*)&vlT[ch * VSTR + row * VROW + oct * 8] = vstage[it].u;
  }
  // zero vlT per-channel pad (overread by tile1 frags at row 11)
  if (tid < DHEAD) {
    const uint4 z = make_uint4(0, 0, 0, 0);
    *(uint4*)&vlT[tid * VSTR + HALO_H * VROW] = z;
  }

  __syncthreads();

  f32x4 oa0 = {0.f, 0.f, 0.f, 0.f};
  f32x4 oa1 = {0.f, 0.f, 0.f, 0.f};
  float den = 0.0f;

  // per-lane LDS bases (byte math folded by compiler into ds offsets)
  const unsigned short* klrow  = &kl[c * KSTR + p * 8];
  const unsigned short* klrow1 = &kl[(16 + c) * KSTR + p * 8];
  const unsigned short* v0row  = &vlT[c * VSTR + 4 * p];
  const unsigned short* v1row  = &vlT[(16 + c) * VSTR + 4 * p];

#pragma unroll
  for (int ry = 0; ry < 7; ++ry) {
    const int hrow = wv + ry;                        // 0..11
    // row-validity folded into QK C operand: invalid -> -16384 bias,
    // exp2(-16384 + s) == 0 exactly (|s| << 150).
    const int gy = gqy + ry - RAD;
    const float bias = ((unsigned)gy < (unsigned)H_IMG) ? 0.0f : -16384.0f;
    const f32x4 ci = {bias, bias, bias, bias};

    // K A-frags: tile0 keys hx 0..15, tile1 keys hx 16..31 (tail masked)
    union { uint4 u; half8_t h; } ka0, ka1;
    ka0.u = *(const uint4*)(klrow  + hrow * (HALO_W * KSTR));
    ka1.u = *(const uint4*)(klrow1 + hrow * (HALO_W * KSTR));

    // V^T A-frags: 4 f16 each — (ch=c / 16+c) x (kslots 4p.. / 16+4p..)
    union { uint2 u; half4_t h; } va00, va01, va10, va11;
    va00.u = *(const uint2*)(v0row + hrow * VROW);
    va01.u = *(const uint2*)(v0row + hrow * VROW + 16);
    va10.u = *(const uint2*)(v1row + hrow * VROW);
    va11.u = *(const uint2*)(v1row + hrow * VROW + 16);

    // S^T = K . Q^T + bias   (col = q, row = key)
    f32x4 s0 = __builtin_amdgcn_mfma_f32_16x16x32_f16(ka0.h, qf, ci, 0, 0, 0);
    f32x4 s1 = __builtin_amdgcn_mfma_f32_16x16x32_f16(ka1.h, qf, ci, 0, 0, 0);

    // p = exp2(s) * mask; accumulate den; pack to f16 pairs (B-frags)
    float pe0[4], pe1[4];
#pragma unroll
    for (int r = 0; r < 4; ++r) {
      pe0[r] = EXP2F(s0[r]) * cm[0][r];
      pe1[r] = EXP2F(s1[r]) * cm[1][r];
      den += pe0[r] + pe1[r];
    }
    union { fp16x2_t h2[2]; half4_t h4; } w0, w1;
    w0.h2[0] = __builtin_amdgcn_cvt_pkrtz(pe0[0], pe0[1]);
    w0.h2[1] = __builtin_amdgcn_cvt_pkrtz(pe0[2], pe0[3]);
    w1.h2[0] = __builtin_amdgcn_cvt_pkrtz(pe1[0], pe1[1]);
    w1.h2[1] = __builtin_amdgcn_cvt_pkrtz(pe1[2], pe1[3]);

    // out^T += V^T . P^T ; lane (c,p) feeds its OWN P values as B-frag
    // (16x16x16 B layout: k = 4*(l>>4)+e = krel 4p+e, t*16 offset per tile)
    oa0 = __builtin_amdgcn_mfma_f32_16x16x16f16(va00.h, w0.h4, oa0, 0, 0, 0);
    oa0 = __builtin_amdgcn_mfma_f32_16x16x16f16(va01.h, w1.h4, oa0, 0, 0, 0);
    oa1 = __builtin_amdgcn_mfma_f32_16x16x16f16(va10.h, w0.h4, oa1, 0, 0, 0);
    oa1 = __builtin_amdgcn_mfma_f32_16x16x16f16(va11.h, w1.h4, oa1, 0, 0, 0);
  }

  // den: lane holds partial over its 8 (tile,reg) keys; sum the 4 p-groups
  den += __shfl_xor(den, 16);
  den += __shfl_xor(den, 32);
  const float rden = 1.0f / den;       // den >= exp(center score) > 0

  // D layout: col=c=q, row=4p+r = ch (oa0: ch 0..15, oa1: ch 16..31)
  const size_t obase = cbase + (size_t)gqy * W_IMG + x0 + c;
#pragma unroll
  for (int r = 0; r < 4; ++r) {
    out[obase + (size_t)(4 * p + r) * PLANE]      = oa0[r] * rden;
    out[obase + (size_t)(16 + 4 * p + r) * PLANE] = oa1[r] * rden;
  }
}

extern "C" void kernel_launch(void* const* d_in, const int* in_sizes, int n_in,
                              void* d_out, int out_size, void* d_ws, size_t ws_size,
                              hipStream_t stream) {
  const float* q = (const float*)d_in[0];
  const float* k = (const float*)d_in[1];
  const float* v = (const float*)d_in[2];
  float* out = (float*)d_out;

  dim3 grid(W_IMG / TW, H_IMG / TH, 4 * NH);   // (3, 8, 32) = 768 blocks
  dim3 block(64, NWAVES, 1);                    // 384 threads = 6 waves
  hipLaunchKernelGGL(natten_f32_kernel, grid, block, 0, stream, q, k, v, out);
}